// Round 2
// baseline (1085.978 us; speedup 1.0000x reference)
//
#include <hip/hip_runtime.h>
#include <hip/hip_fp16.h>
#include <stdint.h>

#define SEQ 512
#define HIDN 512

typedef _Float16 h2_t __attribute__((ext_vector_type(2)));
typedef _Float16 h8_t __attribute__((ext_vector_type(8)));
typedef float f4_t __attribute__((ext_vector_type(4)));

__device__ __forceinline__ float fdot2f(uint32_t a, uint32_t b, float c) {
#if __has_builtin(__builtin_amdgcn_fdot2)
  return __builtin_amdgcn_fdot2(__builtin_bit_cast(h2_t, a),
                                __builtin_bit_cast(h2_t, b), c, false);
#else
  h2_t ah = __builtin_bit_cast(h2_t, a);
  h2_t bh = __builtin_bit_cast(h2_t, b);
  return c + (float)ah.x * (float)bh.x + (float)ah.y * (float)bh.y;
#endif
}

// ---------------- fp32 -> fp16 convert (contiguous) ----------------
__global__ void k_cvt(const float4* __restrict__ src, __half2* __restrict__ dst, int n4) {
  int i = blockIdx.x * blockDim.x + threadIdx.x;
  if (i < n4) {
    float4 v = src[i];
    dst[2 * i]     = __floats2half2_rn(v.x, v.y);
    dst[2 * i + 1] = __floats2half2_rn(v.z, v.w);
  }
}

// ---------------- transpose + convert: dst[c][r] = (half)src[r][c] ----------------
__global__ void k_transpose_cvt(const float* __restrict__ src, __half* __restrict__ dst,
                                int R, int C) {
  __shared__ float tile[32][33];
  int tx = threadIdx.x, ty = threadIdx.y;
  int c0 = blockIdx.x * 32, r0 = blockIdx.y * 32;
#pragma unroll
  for (int i = 0; i < 4; ++i)
    tile[ty + i * 8][tx] = src[(size_t)(r0 + ty + i * 8) * C + c0 + tx];
  __syncthreads();
#pragma unroll
  for (int i = 0; i < 4; ++i)
    dst[(size_t)(c0 + ty + i * 8) * R + r0 + tx] = __float2half(tile[tx][ty + i * 8]);
}

// ---------------- f16 MFMA GEMM: C(MxN,f32) = A(MxK,f16) * Bt(NxK,f16)^T + bias ----------------
__global__ __launch_bounds__(256, 2) void k_gemm(
    const __half* __restrict__ A, const __half* __restrict__ Bt,
    const float* __restrict__ bias, float* __restrict__ C,
    int M, int N, int K) {
  __shared__ __align__(16) __half As[128 * 32];
  __shared__ __align__(16) __half Bs[128 * 32];
  const int tid = threadIdx.x;
  const int m0 = blockIdx.x * 128;
  const int n0 = blockIdx.y * 128;
  const int w = tid >> 6;
  const int lane = tid & 63;
  const int wm = (w >> 1) * 64;
  const int wn = (w & 1) * 64;
  const int fr = lane & 15;   // free-dim index within 16x16 tile
  const int q = lane >> 4;    // k-quad
  const int lr = tid >> 2;    // staging row 0..63
  const int lc = tid & 3;     // staging 16B chunk
  f4_t acc[4][4];
#pragma unroll
  for (int i = 0; i < 4; ++i)
#pragma unroll
    for (int jj = 0; jj < 4; ++jj) acc[i][jj] = (f4_t)(0.f);

  for (int kk = 0; kk < K; kk += 32) {
    *(uint4*)&As[lr * 32 + lc * 8]        = *(const uint4*)&A[(size_t)(m0 + lr) * K + kk + lc * 8];
    *(uint4*)&As[(64 + lr) * 32 + lc * 8] = *(const uint4*)&A[(size_t)(m0 + 64 + lr) * K + kk + lc * 8];
    *(uint4*)&Bs[lr * 32 + lc * 8]        = *(const uint4*)&Bt[(size_t)(n0 + lr) * K + kk + lc * 8];
    *(uint4*)&Bs[(64 + lr) * 32 + lc * 8] = *(const uint4*)&Bt[(size_t)(n0 + 64 + lr) * K + kk + lc * 8];
    __syncthreads();
    h8_t af[4], bf[4];
#pragma unroll
    for (int i = 0; i < 4; ++i) {
      af[i] = *(const h8_t*)&As[(wm + i * 16 + fr) * 32 + q * 8];
      bf[i] = *(const h8_t*)&Bs[(wn + i * 16 + fr) * 32 + q * 8];
    }
#pragma unroll
    for (int i = 0; i < 4; ++i)
#pragma unroll
      for (int jj = 0; jj < 4; ++jj)
        acc[i][jj] = __builtin_amdgcn_mfma_f32_16x16x32_f16(af[i], bf[jj], acc[i][jj], 0, 0, 0);
    __syncthreads();
  }
#pragma unroll
  for (int i = 0; i < 4; ++i) {
    const int row0 = m0 + wm + i * 16 + q * 4;
#pragma unroll
    for (int jj = 0; jj < 4; ++jj) {
      const int col = n0 + wn + jj * 16 + fr;
      const float bv = bias[col];
#pragma unroll
      for (int r = 0; r < 4; ++r)
        C[(size_t)(row0 + r) * N + col] = acc[i][jj][r] + bv;
    }
  }
}

// ---------------- serial recurrence: 64 blocks = (batch, direction) chains ----------------
// Lane j owns Wh column j: 200 f16-pairs in VGPRs + 56 pairs in LDS (112 KB).
// h double-buffered in LDS; one barrier per step; v_dot2_f32_f16 inner product.
// Split 200/56 keeps VGPRs ~235 < 256 cap (launch_bounds 512,2) — spill insurance.
__global__ __launch_bounds__(512, 2) void k_rnn(
    const __half* __restrict__ WhT_f, const __half* __restrict__ WhT_b,
    const float* __restrict__ A_f, const float* __restrict__ A_b,
    __half* __restrict__ bi) {
  __shared__ uint32_t ldsw[56 * HIDN];          // 112 KB: pairs 200..255 of every column
  __shared__ __align__(16) __half hbuf[2][HIDN];
  const int j = threadIdx.x;
  const int d = blockIdx.x & 1;
  const int b = blockIdx.x >> 1;
  const __half* WhT = d ? WhT_b : WhT_f;        // WhT[j][k] = Wh[k][j]
  const float* A = (d ? A_b : A_f) + (size_t)b * SEQ * HIDN;
  __half* birow = bi + (size_t)b * SEQ * 1024 + d * HIDN + j;

  const uint4* wrow = (const uint4*)(WhT + (size_t)j * HIDN);
  uint4 wv[50];
#pragma unroll
  for (int i = 0; i < 50; ++i) wv[i] = wrow[i];
  const uint32_t* wrow32 = (const uint32_t*)wrow;
#pragma unroll
  for (int p = 0; p < 56; ++p) ldsw[p * HIDN + j] = wrow32[200 + p];
  hbuf[0][j] = __float2half(0.f);
  __syncthreads();

  const int tstep = d ? -1 : 1;
  int t = d ? (SEQ - 1) : 0;
  float a_next = A[(size_t)t * HIDN + j];
  int cur = 0;
  for (int s = 0; s < SEQ; ++s) {
    float a_cur = a_next;
    int tn = t + tstep;
    tn = tn < 0 ? 0 : (tn > SEQ - 1 ? SEQ - 1 : tn);
    a_next = A[(size_t)tn * HIDN + j];          // prefetch next step's additive term
    const uint4* hp = (const uint4*)hbuf[cur];
    float acc0 = 0.f, acc1 = 0.f, acc2 = 0.f, acc3 = 0.f;
#pragma unroll
    for (int i = 0; i < 50; ++i) {              // register-resident weights: pairs 0..199
      uint4 hv = hp[i];
      acc0 = fdot2f(hv.x, wv[i].x, acc0);
      acc1 = fdot2f(hv.y, wv[i].y, acc1);
      acc2 = fdot2f(hv.z, wv[i].z, acc2);
      acc3 = fdot2f(hv.w, wv[i].w, acc3);
    }
#pragma unroll
    for (int p4 = 0; p4 < 14; ++p4) {           // LDS-resident weights: pairs 200..255
      uint4 hv = hp[50 + p4];
      acc0 = fdot2f(hv.x, ldsw[(p4 * 4 + 0) * HIDN + j], acc0);
      acc1 = fdot2f(hv.y, ldsw[(p4 * 4 + 1) * HIDN + j], acc1);
      acc2 = fdot2f(hv.z, ldsw[(p4 * 4 + 2) * HIDN + j], acc2);
      acc3 = fdot2f(hv.w, ldsw[(p4 * 4 + 3) * HIDN + j], acc3);
    }
    float p = a_cur + ((acc0 + acc1) + (acc2 + acc3));
    float ap = fabsf(p);
    float e = __expf(2.f * ap);
    float th = 1.f - 2.f * __builtin_amdgcn_rcpf(e + 1.f);  // tanh(|p|)
    float h = copysignf(th, p);
    __half hh = __float2half(h);
    hbuf[cur ^ 1][j] = hh;
    birow[(size_t)t * 1024] = hh;
    cur ^= 1;
    t += tstep;
    __syncthreads();
  }
}

extern "C" void kernel_launch(void* const* d_in, const int* in_sizes, int n_in,
                              void* d_out, int out_size, void* d_ws, size_t ws_size,
                              hipStream_t stream) {
  const float* input_seq = (const float*)d_in[0];  // (32,512,512)
  const float* W_f = (const float*)d_in[1];        // (1024,512)
  const float* b_f = (const float*)d_in[2];
  const float* W_b = (const float*)d_in[3];
  const float* b_b = (const float*)d_in[4];
  const float* W_o = (const float*)d_in[5];        // (1024,512)
  const float* b_o = (const float*)d_in[6];
  float* out = (float*)d_out;

  char* ws = (char*)d_ws;
  // workspace layout (needs ~121 MB)
  __half* Xh    = (__half*)(ws);                    // 16 MB  (16384x512 f16)
  float*  A_f   = (float*)(ws + 16777216);          // 32 MB  (x@Wx_f + b_f, fp32)
  float*  A_b   = (float*)(ws + 50331648);          // 32 MB
  __half* bi    = (__half*)(ws + 83886080);         // 32 MB  (16384x1024 f16)
  __half* WxT_f = (__half*)(ws + 117440512);        // 512 KB (512x512, [j][e])
  __half* WxT_b = (__half*)(ws + 117964800);
  __half* WhT_f = (__half*)(ws + 118489088);        // 512 KB (512x512, [j][k])
  __half* WhT_b = (__half*)(ws + 119013376);
  __half* WoT   = (__half*)(ws + 119537664);        // 1 MB   (512x1024, [o][c])

  // Stage 1: conversions / transposes
  k_cvt<<<8192, 256, 0, stream>>>((const float4*)input_seq, (__half2*)Xh, 2097152);
  dim3 tb(32, 8);
  k_transpose_cvt<<<dim3(16, 16), tb, 0, stream>>>(W_f,          WxT_f, 512, 512);
  k_transpose_cvt<<<dim3(16, 16), tb, 0, stream>>>(W_f + 262144, WhT_f, 512, 512);
  k_transpose_cvt<<<dim3(16, 16), tb, 0, stream>>>(W_b,          WxT_b, 512, 512);
  k_transpose_cvt<<<dim3(16, 16), tb, 0, stream>>>(W_b + 262144, WhT_b, 512, 512);
  k_transpose_cvt<<<dim3(16, 32), tb, 0, stream>>>(W_o,          WoT, 1024, 512);

  // Stage 2: A_d = X @ Wx_d + b_d   (M=16384, N=512, K=512)
  k_gemm<<<dim3(128, 4), 256, 0, stream>>>(Xh, WxT_f, b_f, A_f, 16384, 512, 512);
  k_gemm<<<dim3(128, 4), 256, 0, stream>>>(Xh, WxT_b, b_b, A_b, 16384, 512, 512);

  // Stage 3: serial recurrence, both directions -> bi (f16, concat layout)
  k_rnn<<<64, 512, 0, stream>>>(WhT_f, WhT_b, A_f, A_b, bi);

  // Stage 4: out = bi @ W_o + b_o   (M=16384, N=512, K=1024)
  k_gemm<<<dim3(128, 4), 256, 0, stream>>>(bi, WoT, b_o, out, 16384, 512, 1024);
}